// Round 8
// baseline (466.830 us; speedup 1.0000x reference)
//
#include <hip/hip_runtime.h>
#include <hip/hip_bf16.h>

// BlockSparseLinear: y = x @ W^T + b
// Round 9: register-double-buffered A prefetch (T14 issue-early/consume-late).
// Round-8 post-mortem: direct-global A kept traffic fine (FETCH 237MB) but
// single-buffered a-regs forced the a1 prefetch to issue right before the
// barrier -> every kb exposed a full L2 round-trip (MfmaUtil 17.9, idle 82%).
// Fix: TWO a-register sets; the ENTIRE next-kb prefetch (2 W-DMA + 8 a-loads)
// issues at the TOP of each iteration into the other set, covered by the
// whole iteration (~500+cyc). Register math (a-dbuf 64 + acc 64 + b/addr ~40
// = ~170 unified) forces 256-thread blocks: __launch_bounds__(256,3) -> 3
// blocks/CU = 12 waves/CU (512-thread would cliff to 1 blk/CU at >128 regs).
// Cost: TM=256 halves W amortization (W transit ~256MB, L3-resident) - traded
// against removing the per-kb latency exposure.
// vmcnt ledger: top vmcnt(0) drains 8 prefetched a-loads; issue 2 W + 8 a'
// (10 outstanding); bottom vmcnt(8) retires exactly the 2 W; 8 a' cross the
// barrier. One tight s_barrier per kb (lock-step = L2 locality, round-7).
// Unroll x2 with NAMED register sets (rule #20: no runtime-indexed reg arrays).

#define NTHREADS 256    // 4 waves
#define TM 256          // tokens per workgroup tile
#define KNZ 16          // nonzero col-blocks per row-block

typedef __attribute__((ext_vector_type(8))) short short8;    // bf16 x8 (16 B)
typedef __attribute__((ext_vector_type(4))) float floatx4;

__device__ __forceinline__ unsigned short f2bf(float f) {
    unsigned u = __float_as_uint(f);
    u += 0x7fffu + ((u >> 16) & 1u);
    return (unsigned short)(u >> 16);
}

// async 16B global -> LDS DMA; lds base must be wave-uniform, dest = base + lane*16
__device__ __forceinline__ void gl_lds_16(const void* g, void* l) {
    __builtin_amdgcn_global_load_lds(
        (const __attribute__((address_space(1))) unsigned int*)g,
        (__attribute__((address_space(3))) unsigned int*)l,
        16, 0, 0);
}

// ---- Kernel 1: fp32 -> bf16 conversion (x then w) ----
#define CVT_THREADS 256
__global__ __launch_bounds__(CVT_THREADS)
void cvt_kernel(const float* __restrict__ x, const float* __restrict__ w,
                unsigned short* __restrict__ xb, unsigned short* __restrict__ wb,
                int n_x8, int n_w8)
{
    int g = blockIdx.x * CVT_THREADS + threadIdx.x;
    const float* src;
    unsigned short* dst;
    if (g < n_x8) { src = x + (size_t)g * 8; dst = xb + (size_t)g * 8; }
    else {
        int h = g - n_x8;
        if (h >= n_w8) return;
        src = w + (size_t)h * 8; dst = wb + (size_t)h * 8;
    }
    floatx4 v0 = *(const floatx4*)(src);
    floatx4 v1 = *(const floatx4*)(src + 4);
    union { ushort4 u4[2]; short8 s8; } p;
    p.u4[0].x = f2bf(v0.x); p.u4[0].y = f2bf(v0.y);
    p.u4[0].z = f2bf(v0.z); p.u4[0].w = f2bf(v0.w);
    p.u4[1].x = f2bf(v1.x); p.u4[1].y = f2bf(v1.y);
    p.u4[1].z = f2bf(v1.z); p.u4[1].w = f2bf(v1.w);
    *(short8*)dst = p.s8;
}

// ---- Kernel 2: bf16 MFMA GEMM; reg-dbuf A prefetch, LDS dbuf W ----
__global__ __launch_bounds__(NTHREADS, 3)   // 3 waves/SIMD -> 3 blocks/CU
void bsl_mfma_bf16_kernel(const unsigned short* __restrict__ xb,
                          const unsigned short* __restrict__ wb,
                          const float* __restrict__ bias,
                          const int* __restrict__ col_idx,
                          float* __restrict__ out,
                          int n_tiles)
{
    __shared__ unsigned short Ws[2][64 * 64];   // 16 KB

    // XCD swizzle, rb-major within XCD: X slab (2MB) stays L2-hot while all
    // 64 rb-blocks consume it; W refetches per tt from L3 (the cheaper trade).
    int id = blockIdx.x;
    int rb, tt;
    if ((n_tiles & 7) == 0) {
        int xcd  = id & 7;
        int slot = id >> 3;
        int tpx  = n_tiles >> 3;
        rb = slot & 63;
        tt = xcd * tpx + (slot >> 6);
    } else {
        rb = id & 63;
        tt = id >> 6;
    }

    const int tid  = threadIdx.x;
    const int lane = tid & 63;
    const int wv   = tid >> 6;       // 0..3
    const int l15  = lane & 15;
    const int l4   = lane >> 4;
    const int tok0 = tt * TM;
    const int lr   = lane >> 3;      // 0..7: row within a W DMA wave-load
    const int lc   = lane & 7;       // 0..7: swizzled chunk slot

    floatx4 acc[4][4];
    #pragma unroll
    for (int i = 0; i < 4; ++i)
        #pragma unroll
        for (int j = 0; j < 4; ++j)
            acc[i][j] = (floatx4){0.f, 0.f, 0.f, 0.f};

    // W block kb -> Ws[buf]; 2 DMA ops per wave (4 waves cover 8 KB).
    // LDS slot holds global chunk c8 = (lane&7) ^ (row&7)  (XOR swizzle).
    auto dma_w = [&](int buf, int kb) {
        const unsigned short* wsrc = wb + (size_t)(rb * KNZ + kb) * 4096;
        #pragma unroll
        for (int j = 0; j < 2; ++j) {
            int L   = wv * 2 + j;
            int row = L * 8 + lr;
            int c8  = lc ^ (row & 7);
            gl_lds_16(wsrc + row * 64 + c8 * 8, &Ws[buf][L * 512]);
        }
    };

    const int* ci = col_idx + rb * KNZ;

    // Per-lane A base: row = tok0 + wv*64 + l15 (+16 per mt), k-chunk = l4.
    const unsigned short* xrow =
        xb + ((size_t)tok0 + (size_t)wv * 64 + l15) * 4096 + l4 * 8;

    // Issue the 8 a-loads for col-block cb into (a0,a1).
    auto load_a = [&](short8* a0, short8* a1, int cb) {
        const unsigned short* xp = xrow + (size_t)cb * 64;
        #pragma unroll
        for (int mt = 0; mt < 4; ++mt)
            a0[mt] = *(const short8*)(xp + mt * 65536);
        #pragma unroll
        for (int mt = 0; mt < 4; ++mt)
            a1[mt] = *(const short8*)(xp + mt * 65536 + 32);
    };

    const int swA = (l4 ^ (l15 & 7)) * 8;          // ks=0 swizzled W chunk
    const int swB = ((4 + l4) ^ (l15 & 7)) * 8;    // ks=1

    short8 aA0[4], aA1[4], aB0[4], aB1[4];         // two named register sets

    // Prologue: W(0) (2 ops) then a(0) (8 ops); retire W pair, publish.
    dma_w(0, 0);
    load_a(aA0, aA1, ci[0]);
    asm volatile("s_waitcnt vmcnt(8)" ::: "memory");   // 2 W retired, 8 a fly
    __builtin_amdgcn_sched_barrier(0);
    __builtin_amdgcn_s_barrier();                      // publish W(0)

    // One kb step: consume (c0,c1), prefetch kb+1 into (n0,n1).
    auto body = [&](short8* c0, short8* c1, short8* n0, short8* n1, int kb) {
        const int cur = kb & 1;
        const bool has_next = (kb + 1 < KNZ);

        // Prefetched a(kb) landed (W(kb) was retired before the barrier).
        asm volatile("s_waitcnt vmcnt(0)" ::: "memory");
        __builtin_amdgcn_sched_barrier(0);

        // FULL next-tile prefetch at the top: W first (oldest -> bottom
        // vmcnt(8) retires it), then the 8 a'-loads into the OTHER reg set.
        // Covered by everything below (~2 ds_read waits + 32 MFMAs + barrier).
        if (has_next) {
            dma_w(cur ^ 1, kb + 1);
            load_a(n0, n1, ci[kb + 1]);
        }

        short8 b[4];
        #pragma unroll
        for (int nt = 0; nt < 4; ++nt)
            b[nt] = *(const short8*)&Ws[cur][(nt * 16 + l15) * 64 + swA];
        asm volatile("s_waitcnt lgkmcnt(0)" ::: "memory");
        __builtin_amdgcn_sched_barrier(0);

        __builtin_amdgcn_s_setprio(1);
        #pragma unroll
        for (int mt = 0; mt < 4; ++mt)
            #pragma unroll
            for (int nt = 0; nt < 4; ++nt)
                acc[mt][nt] = __builtin_amdgcn_mfma_f32_16x16x32_bf16(
                    c0[mt], b[nt], acc[mt][nt], 0, 0, 0);
        __builtin_amdgcn_s_setprio(0);
        __builtin_amdgcn_sched_barrier(0);

        #pragma unroll
        for (int nt = 0; nt < 4; ++nt)
            b[nt] = *(const short8*)&Ws[cur][(nt * 16 + l15) * 64 + swB];
        asm volatile("s_waitcnt lgkmcnt(0)" ::: "memory");
        __builtin_amdgcn_sched_barrier(0);

        __builtin_amdgcn_s_setprio(1);
        #pragma unroll
        for (int mt = 0; mt < 4; ++mt)
            #pragma unroll
            for (int nt = 0; nt < 4; ++nt)
                acc[mt][nt] = __builtin_amdgcn_mfma_f32_16x16x32_bf16(
                    c1[mt], b[nt], acc[mt][nt], 0, 0, 0);
        __builtin_amdgcn_s_setprio(0);
        __builtin_amdgcn_sched_barrier(0);

        if (has_next) {
            // Outstanding: 2 W + 8 a'. Retire the W pair only; the 8 a'
            // survive the barrier and are waited at the next top.
            asm volatile("s_waitcnt vmcnt(8)" ::: "memory");
            __builtin_amdgcn_sched_barrier(0);
            __builtin_amdgcn_s_barrier();          // publish W(kb+1)
        }
    };

    // Unrolled x2: compile-time register-set roles (rule #20).
    for (int kb = 0; kb < KNZ; kb += 2) {
        body(aA0, aA1, aB0, aB1, kb);
        body(aB0, aB1, aA0, aA1, kb + 1);
    }

    // Epilogue: C/D layout col = lane&15, row = (lane>>4)*4 + reg.
    const int ocol0 = rb * 64;
    #pragma unroll
    for (int nt = 0; nt < 4; ++nt) {
        const int col = ocol0 + nt * 16 + l15;
        const float bv = bias[col];
        #pragma unroll
        for (int mt = 0; mt < 4; ++mt) {
            const size_t trow = (size_t)tok0 + wv * 64 + mt * 16 + l4 * 4;
            float* op = out + trow * 4096 + col;
            #pragma unroll
            for (int r = 0; r < 4; ++r)
                op[(size_t)r * 4096] = acc[mt][nt][r] + bv;
        }
    }
}

// ---- Fallback (fp32 direct) if ws too small ---- (256 threads, TM=256)
#define TMF 256
#define NTF 256
#define XS_LD 72
#define WS_LD 72
__global__ __launch_bounds__(NTF)
void bsl_mfma_f32_kernel(const float* __restrict__ x,
                         const float* __restrict__ w,
                         const float* __restrict__ bias,
                         const int* __restrict__ col_idx,
                         float* __restrict__ out)
{
    __shared__ unsigned short Xs[TMF * XS_LD];
    __shared__ unsigned short Ws[64 * WS_LD];
    const int rb = blockIdx.x, tt = blockIdx.y;
    const int tid = threadIdx.x, lane = tid & 63, wv = tid >> 6;
    const int l15 = lane & 15, l4 = lane >> 4, tok0 = tt * TMF;
    floatx4 acc[4][4];
    #pragma unroll
    for (int i = 0; i < 4; ++i)
        #pragma unroll
        for (int j = 0; j < 4; ++j) acc[i][j] = (floatx4){0.f,0.f,0.f,0.f};
    for (int kb = 0; kb < KNZ; ++kb) {
        const int nz = rb * KNZ + kb;
        const int cb = col_idx[nz];
        const float* xsrc = x + (size_t)tok0 * 4096 + (size_t)cb * 64;
        const float* wsrc = w + (size_t)nz * 4096;
        __syncthreads();
        #pragma unroll
        for (int i = 0; i < 16; ++i) {
            int f = i * NTF + tid, row = f >> 4, c4 = f & 15;
            floatx4 v = *(const floatx4*)(xsrc + (size_t)row * 4096 + c4 * 4);
            ushort4 p; p.x=f2bf(v.x); p.y=f2bf(v.y); p.z=f2bf(v.z); p.w=f2bf(v.w);
            *(ushort4*)&Xs[row * XS_LD + c4 * 4] = p;
        }
        #pragma unroll
        for (int i = 0; i < 4; ++i) {
            int f = i * NTF + tid, row = f >> 4, c4 = f & 15;
            floatx4 v = *(const floatx4*)(wsrc + row * 64 + c4 * 4);
            ushort4 p; p.x=f2bf(v.x); p.y=f2bf(v.y); p.z=f2bf(v.z); p.w=f2bf(v.w);
            *(ushort4*)&Ws[row * WS_LD + c4 * 4] = p;
        }
        __syncthreads();
        #pragma unroll
        for (int ks = 0; ks < 2; ++ks) {
            const int k0 = ks * 32 + l4 * 8;
            short8 a[4], b[4];
            #pragma unroll
            for (int mt = 0; mt < 4; ++mt)
                a[mt] = *(const short8*)&Xs[(wv*64 + mt*16 + l15) * XS_LD + k0];
            #pragma unroll
            for (int nt = 0; nt < 4; ++nt)
                b[nt] = *(const short8*)&Ws[(nt*16 + l15) * WS_LD + k0];
            #pragma unroll
            for (int mt = 0; mt < 4; ++mt)
                #pragma unroll
                for (int nt = 0; nt < 4; ++nt)
                    acc[mt][nt] = __builtin_amdgcn_mfma_f32_16x16x32_bf16(
                        a[mt], b[nt], acc[mt][nt], 0, 0, 0);
        }
    }
    const int ocol0 = rb * 64;
    #pragma unroll
    for (int nt = 0; nt < 4; ++nt) {
        const int col = ocol0 + nt * 16 + l15;
        const float bv = bias[col];
        #pragma unroll
        for (int mt = 0; mt < 4; ++mt) {
            const size_t trow = (size_t)tok0 + wv * 64 + mt * 16 + l4 * 4;
            float* op = out + trow * 4096 + col;
            #pragma unroll
            for (int r = 0; r < 4; ++r)
                op[(size_t)r * 4096] = acc[mt][nt][r] + bv;
        }
    }
}

extern "C" void kernel_launch(void* const* d_in, const int* in_sizes, int n_in,
                              void* d_out, int out_size, void* d_ws, size_t ws_size,
                              hipStream_t stream) {
    const float* x       = (const float*)d_in[0];
    const float* w       = (const float*)d_in[1];
    const float* bias    = (const float*)d_in[2];
    const int*   col_idx = (const int*)d_in[4];
    float*       out     = (float*)d_out;

    const int n_x = in_sizes[0];
    const int n_w = in_sizes[1];
    const int n_tok = n_x / 4096;
    const size_t need = (size_t)(n_x + n_w) * 2;

    if (ws_size >= need && (n_tok % TM) == 0) {
        unsigned short* xb = (unsigned short*)d_ws;
        unsigned short* wb = xb + n_x;
        int n_x8 = n_x / 8, n_w8 = n_w / 8;
        int total = n_x8 + n_w8;
        cvt_kernel<<<(total + CVT_THREADS - 1) / CVT_THREADS, CVT_THREADS, 0, stream>>>(
            x, w, xb, wb, n_x8, n_w8);
        int n_tiles = n_tok / TM;
        bsl_mfma_bf16_kernel<<<64 * n_tiles, NTHREADS, 0, stream>>>(
            xb, wb, bias, col_idx, out, n_tiles);
    } else {
        dim3 grid(64, n_tok / TMF);
        bsl_mfma_f32_kernel<<<grid, NTF, 0, stream>>>(x, w, bias, col_idx, out);
    }
}